// Round 2
// baseline (792.712 us; speedup 1.0000x reference)
//
#include <hip/hip_runtime.h>
#include <hip/hip_bf16.h>

typedef __bf16 bf16;
typedef __bf16 bf16x4 __attribute__((ext_vector_type(4)));
typedef __bf16 bf16x8 __attribute__((ext_vector_type(8)));
typedef float f32x4 __attribute__((ext_vector_type(4)));

#define MFMA16(a, b, c) __builtin_amdgcn_mfma_f32_16x16x32_bf16(a, b, c, 0, 0, 0)

constexpr int DIM = 1024;
constexpr int NH = 16;
constexpr int HD = 64;
constexpr float SCALE = 0.125f;          // HEAD_DIM^-0.5
constexpr float L2E = 1.4426950408889634f;
constexpr float SCL2E = SCALE * L2E;     // fold softmax into exp2 domain

// ---------------------------------------------------------------------------
// NT GEMM: C[M,1024] = A[M,1024] @ W[1024,1024]^T + bias
// OUT_MODE 0: fp32 row-major [M,1024]
// OUT_MODE 1: bf16 head-major [B, NH, Lq, 64]
// OUT_MODE 2: bf16 V-transposed [B, NH, 64, Lq]   (Lq must be 1024)
// A_BF16: A operand already bf16 (attention output)
// 128x128 tile, 4 waves (2x2 of 64x64), BK=64 (2 sub-steps of 32).
// ---------------------------------------------------------------------------
template <int OUT_MODE, bool A_BF16>
__global__ __launch_bounds__(256) void gemm_nt(const void* __restrict__ Aptr,
                                               const float* __restrict__ W,
                                               const float* __restrict__ bias,
                                               void* __restrict__ Cptr, int Lq) {
  constexpr int LDT = 72;  // padded row stride (elems): 144B, 16B-aligned
  __shared__ bf16 As[128 * LDT];
  __shared__ bf16 Bs[128 * LDT];

  const int bm = blockIdx.x * 128;
  const int bn = blockIdx.y * 128;
  const int tid = threadIdx.x;
  const int w = tid >> 6;
  const int lane = tid & 63;
  const int quad = lane >> 4;
  const int l16 = lane & 15;
  const int wm = (w >> 1) * 64;
  const int wn = (w & 1) * 64;

  f32x4 acc[4][4] = {};

  for (int k0 = 0; k0 < DIM; k0 += 64) {
    // ---- stage W tile (rows bn..bn+127, cols k0..k0+63), fp32 -> bf16
#pragma unroll
    for (int i = 0; i < 8; ++i) {
      int f = i * 256 + tid;              // float4 chunk id, 0..2047
      int row = f >> 4;
      int c4 = (f & 15) << 2;
      const float4 v = *(const float4*)(W + (size_t)(bn + row) * DIM + k0 + c4);
      bf16x4 bv = {(bf16)v.x, (bf16)v.y, (bf16)v.z, (bf16)v.w};
      *(bf16x4*)&Bs[row * LDT + c4] = bv;
    }
    // ---- stage A tile
    if constexpr (A_BF16) {
      const bf16* A = (const bf16*)Aptr;
#pragma unroll
      for (int i = 0; i < 4; ++i) {
        int f = i * 256 + tid;            // 16B chunk id
        int row = f >> 3;
        int c8 = (f & 7) << 3;
        *(bf16x8*)&As[row * LDT + c8] =
            *(const bf16x8*)(A + (size_t)(bm + row) * DIM + k0 + c8);
      }
    } else {
      const float* A = (const float*)Aptr;
#pragma unroll
      for (int i = 0; i < 8; ++i) {
        int f = i * 256 + tid;
        int row = f >> 4;
        int c4 = (f & 15) << 2;
        const float4 v = *(const float4*)(A + (size_t)(bm + row) * DIM + k0 + c4);
        bf16x4 av = {(bf16)v.x, (bf16)v.y, (bf16)v.z, (bf16)v.w};
        *(bf16x4*)&As[row * LDT + c4] = av;
      }
    }
    __syncthreads();

#pragma unroll
    for (int sub = 0; sub < 2; ++sub) {
      bf16x8 af[4], bfr[4];
#pragma unroll
      for (int mi = 0; mi < 4; ++mi)
        af[mi] = *(const bf16x8*)&As[(wm + mi * 16 + l16) * LDT + sub * 32 + quad * 8];
#pragma unroll
      for (int ni = 0; ni < 4; ++ni)
        bfr[ni] = *(const bf16x8*)&Bs[(wn + ni * 16 + l16) * LDT + sub * 32 + quad * 8];
#pragma unroll
      for (int mi = 0; mi < 4; ++mi)
#pragma unroll
        for (int ni = 0; ni < 4; ++ni)
          acc[mi][ni] = MFMA16(af[mi], bfr[ni], acc[mi][ni]);
    }
    __syncthreads();
  }

  // ---- epilogue: C/D layout col = lane&15, row = quad*4 + r
#pragma unroll
  for (int mi = 0; mi < 4; ++mi) {
#pragma unroll
    for (int ni = 0; ni < 4; ++ni) {
      const int col = bn + wn + ni * 16 + l16;
      const float bv = bias[col];
#pragma unroll
      for (int r = 0; r < 4; ++r) {
        const int row = bm + wm + mi * 16 + quad * 4 + r;
        const float val = acc[mi][ni][r] + bv;
        if constexpr (OUT_MODE == 0) {
          ((float*)Cptr)[(size_t)row * DIM + col] = val;
        } else if constexpr (OUT_MODE == 1) {
          const int b = row / Lq;
          const int l = row - b * Lq;
          ((bf16*)Cptr)[((size_t)((b * NH + (col >> 6)) * Lq + l) << 6) + (col & 63)] =
              (bf16)val;
        } else {  // V^T [b, h, d, kv], Lq == 1024
          const int b = row >> 10;
          const int kv = row & 1023;
          ((bf16*)Cptr)[(((size_t)(b * NH + (col >> 6)) << 6) + (col & 63)) * 1024 + kv] =
              (bf16)val;
        }
      }
    }
  }
}

// ---------------------------------------------------------------------------
// Flash-style cross attention, transposed formulation.
//   S^T = K Q^T  (A = K: m=kv, B = Q: n=q)  -> lane owns ONE q row (l16)
//   O^T = V^T P^T (A = V^T: m=d,  B = P^T: n=q)
// Q: bf16 [B,NH,4096,64]  K: bf16 [B,NH,1024,64]  VT: bf16 [B,NH,64,1024]
// O: bf16 [B,4096,1024] (col = h*64+d)
// No running max (scores bounded; exp2 clamped), no barriers in the k-loop.
// grid (L/64, NH, B), 4 waves; wave w owns q rows w*16..w*16+15.
// ---------------------------------------------------------------------------
__global__ __launch_bounds__(256) void attn_fused(const bf16* __restrict__ Q,
                                                  const bf16* __restrict__ K,
                                                  const bf16* __restrict__ VT,
                                                  bf16* __restrict__ O) {
  constexpr int LDP = 72;  // P^T row stride: 144B -> only free 2-way conflicts
  __shared__ bf16 Ptq[4][16 * LDP];  // per-wave: [q_local=16][kv_local=64]

  const int qt = blockIdx.x;
  const int h = blockIdx.y;
  const int b = blockIdx.z;
  const int tid = threadIdx.x;
  const int w = tid >> 6;
  const int lane = tid & 63;
  const int quad = lane >> 4;
  const int l16 = lane & 15;

  const bf16* Qr = Q + ((size_t)(b * NH + h) * 4096 + qt * 64 + w * 16 + l16) * HD;
  const bf16* Kb = K + (size_t)(b * NH + h) * 1024 * HD;
  const bf16* Vb = VT + (size_t)(b * NH + h) * HD * 1024;
  bf16* Pw = &Ptq[w][0];

  // Q as B-operand: B[k=d][n=q], lane n=l16, k=quad*8+j; two 32-wide k chunks
  const bf16x8 qf0 = *(const bf16x8*)(Qr + quad * 8);
  const bf16x8 qf1 = *(const bf16x8*)(Qr + 32 + quad * 8);

  f32x4 oacc[4] = {};
  float lrun = 0.f;

  for (int kt = 0; kt < 1024; kt += 64) {
    // ---- S^T tile: 64 kv rows x 16 q cols (this wave's q block)
#pragma unroll
    for (int nt = 0; nt < 4; ++nt) {
      const bf16* kr = Kb + (size_t)(kt + nt * 16 + l16) * HD;  // A[m=kv][k=d]
      bf16x8 kf0 = *(const bf16x8*)(kr + quad * 8);
      bf16x8 kf1 = *(const bf16x8*)(kr + 32 + quad * 8);
      f32x4 a = {0.f, 0.f, 0.f, 0.f};
      a = MFMA16(kf0, qf0, a);
      a = MFMA16(kf1, qf1, a);
      // lane holds S^T[kv = kt+nt*16+quad*4+r][q = l16]
      bf16x4 pb;
#pragma unroll
      for (int r = 0; r < 4; ++r) {
        const float p = __builtin_exp2f(fminf(a[r] * SCL2E, 80.f));
        lrun += p;
        pb[r] = (bf16)p;
      }
      *(bf16x4*)(Pw + l16 * LDP + nt * 16 + quad * 4) = pb;  // vectorized 8B
    }

    // ---- P^T B-fragments: lane n=q=l16, k=kv=quad*8+j  (ds_read_b128)
    const bf16x8 pf0 = *(const bf16x8*)(Pw + l16 * LDP + quad * 8);
    const bf16x8 pf1 = *(const bf16x8*)(Pw + l16 * LDP + 32 + quad * 8);

    // ---- O^T += V^T P^T
#pragma unroll
    for (int dt = 0; dt < 4; ++dt) {
      const bf16* vr = Vb + (size_t)(dt * 16 + l16) * 1024 + kt;  // A[m=d][k=kv]
      bf16x8 vf0 = *(const bf16x8*)(vr + quad * 8);
      bf16x8 vf1 = *(const bf16x8*)(vr + 32 + quad * 8);
      oacc[dt] = MFMA16(vf0, pf0, oacc[dt]);
      oacc[dt] = MFMA16(vf1, pf1, oacc[dt]);
    }
  }

  // ---- finalize: total l across the 4 quads holding this q's kv partials
  lrun += __shfl_xor(lrun, 16);
  lrun += __shfl_xor(lrun, 32);
  const float inv = 1.f / lrun;

  // O^T D-layout: lane n=q=l16, rows d = dt*16 + quad*4 + r
  const size_t orow = ((size_t)(b * 4096 + qt * 64 + w * 16 + l16)) * DIM + h * 64;
#pragma unroll
  for (int dt = 0; dt < 4; ++dt) {
    bf16x4 ov = {(bf16)(oacc[dt][0] * inv), (bf16)(oacc[dt][1] * inv),
                 (bf16)(oacc[dt][2] * inv), (bf16)(oacc[dt][3] * inv)};
    *(bf16x4*)(O + orow + dt * 16 + quad * 4) = ov;
  }
}

// ---------------------------------------------------------------------------
extern "C" void kernel_launch(void* const* d_in, const int* in_sizes, int n_in,
                              void* d_out, int out_size, void* d_ws, size_t ws_size,
                              hipStream_t stream) {
  const float* x_broad = (const float*)d_in[0];
  const float* x_low = (const float*)d_in[1];
  const float* Wq = (const float*)d_in[2];
  const float* bq = (const float*)d_in[3];
  const float* Wk = (const float*)d_in[4];
  const float* bk = (const float*)d_in[5];
  const float* Wv = (const float*)d_in[6];
  const float* bv = (const float*)d_in[7];
  const float* Wo = (const float*)d_in[8];
  const float* bo = (const float*)d_in[9];

  constexpr int B = 4, L = 4096, LL = 1024;

  // workspace (bf16): Q[B,NH,L,64] | K[B,NH,LL,64] | VT[B,NH,64,LL] | O[B,L,DIM]
  char* ws = (char*)d_ws;
  const size_t qBytes = (size_t)B * NH * L * HD * sizeof(bf16);
  const size_t kvBytes = (size_t)B * NH * LL * HD * sizeof(bf16);
  bf16* Qw = (bf16*)ws;
  bf16* Kw = (bf16*)(ws + qBytes);
  bf16* Vw = (bf16*)(ws + qBytes + kvBytes);
  bf16* Ow = (bf16*)(ws + qBytes + 2 * kvBytes);

  const dim3 blk(256);
  hipLaunchKernelGGL((gemm_nt<1, false>), dim3(B * L / 128, DIM / 128), blk, 0,
                     stream, x_broad, Wq, bq, Qw, L);
  hipLaunchKernelGGL((gemm_nt<1, false>), dim3(B * LL / 128, DIM / 128), blk, 0,
                     stream, x_low, Wk, bk, Kw, LL);
  hipLaunchKernelGGL((gemm_nt<2, false>), dim3(B * LL / 128, DIM / 128), blk, 0,
                     stream, x_low, Wv, bv, Vw, LL);
  hipLaunchKernelGGL(attn_fused, dim3(L / 64, NH, B), blk, 0, stream, Qw, Kw, Vw, Ow);
  hipLaunchKernelGGL((gemm_nt<0, true>), dim3(B * L / 128, DIM / 128), blk, 0,
                     stream, Ow, Wo, bo, d_out, 1);
}

// Round 3
// 581.958 us; speedup vs baseline: 1.3621x; 1.3621x over previous
//
#include <hip/hip_runtime.h>
#include <hip/hip_bf16.h>

typedef __bf16 bf16;
typedef __bf16 bf16x4 __attribute__((ext_vector_type(4)));
typedef __bf16 bf16x8 __attribute__((ext_vector_type(8)));
typedef float f32x4 __attribute__((ext_vector_type(4)));

#define MFMA16(a, b, c) __builtin_amdgcn_mfma_f32_16x16x32_bf16(a, b, c, 0, 0, 0)

constexpr int DIM = 1024;
constexpr int NH = 16;
constexpr int HD = 64;
constexpr float SCALE = 0.125f;          // HEAD_DIM^-0.5
constexpr float L2E = 1.4426950408889634f;
constexpr float SCL2E = SCALE * L2E;     // fold softmax scale into exp2 domain

// ---------------------------------------------------------------------------
// NT GEMM: C[M,1024] = A[M,1024] @ W[1024,1024]^T + bias  (unchanged from R2)
// OUT_MODE 0: fp32 row-major; 1: bf16 head-major [B,NH,Lq,64]; 2: bf16 V^T.
// ---------------------------------------------------------------------------
template <int OUT_MODE, bool A_BF16>
__global__ __launch_bounds__(256) void gemm_nt(const void* __restrict__ Aptr,
                                               const float* __restrict__ W,
                                               const float* __restrict__ bias,
                                               void* __restrict__ Cptr, int Lq) {
  constexpr int LDT = 72;
  __shared__ bf16 As[128 * LDT];
  __shared__ bf16 Bs[128 * LDT];

  const int bm = blockIdx.x * 128;
  const int bn = blockIdx.y * 128;
  const int tid = threadIdx.x;
  const int w = tid >> 6;
  const int lane = tid & 63;
  const int quad = lane >> 4;
  const int l16 = lane & 15;
  const int wm = (w >> 1) * 64;
  const int wn = (w & 1) * 64;

  f32x4 acc[4][4] = {};

  for (int k0 = 0; k0 < DIM; k0 += 64) {
#pragma unroll
    for (int i = 0; i < 8; ++i) {
      int f = i * 256 + tid;
      int row = f >> 4;
      int c4 = (f & 15) << 2;
      const float4 v = *(const float4*)(W + (size_t)(bn + row) * DIM + k0 + c4);
      bf16x4 bv = {(bf16)v.x, (bf16)v.y, (bf16)v.z, (bf16)v.w};
      *(bf16x4*)&Bs[row * LDT + c4] = bv;
    }
    if constexpr (A_BF16) {
      const bf16* A = (const bf16*)Aptr;
#pragma unroll
      for (int i = 0; i < 4; ++i) {
        int f = i * 256 + tid;
        int row = f >> 3;
        int c8 = (f & 7) << 3;
        *(bf16x8*)&As[row * LDT + c8] =
            *(const bf16x8*)(A + (size_t)(bm + row) * DIM + k0 + c8);
      }
    } else {
      const float* A = (const float*)Aptr;
#pragma unroll
      for (int i = 0; i < 8; ++i) {
        int f = i * 256 + tid;
        int row = f >> 4;
        int c4 = (f & 15) << 2;
        const float4 v = *(const float4*)(A + (size_t)(bm + row) * DIM + k0 + c4);
        bf16x4 av = {(bf16)v.x, (bf16)v.y, (bf16)v.z, (bf16)v.w};
        *(bf16x4*)&As[row * LDT + c4] = av;
      }
    }
    __syncthreads();

#pragma unroll
    for (int sub = 0; sub < 2; ++sub) {
      bf16x8 af[4], bfr[4];
#pragma unroll
      for (int mi = 0; mi < 4; ++mi)
        af[mi] = *(const bf16x8*)&As[(wm + mi * 16 + l16) * LDT + sub * 32 + quad * 8];
#pragma unroll
      for (int ni = 0; ni < 4; ++ni)
        bfr[ni] = *(const bf16x8*)&Bs[(wn + ni * 16 + l16) * LDT + sub * 32 + quad * 8];
#pragma unroll
      for (int mi = 0; mi < 4; ++mi)
#pragma unroll
        for (int ni = 0; ni < 4; ++ni)
          acc[mi][ni] = MFMA16(af[mi], bfr[ni], acc[mi][ni]);
    }
    __syncthreads();
  }

#pragma unroll
  for (int mi = 0; mi < 4; ++mi) {
#pragma unroll
    for (int ni = 0; ni < 4; ++ni) {
      const int col = bn + wn + ni * 16 + l16;
      const float bv = bias[col];
#pragma unroll
      for (int r = 0; r < 4; ++r) {
        const int row = bm + wm + mi * 16 + quad * 4 + r;
        const float val = acc[mi][ni][r] + bv;
        if constexpr (OUT_MODE == 0) {
          ((float*)Cptr)[(size_t)row * DIM + col] = val;
        } else if constexpr (OUT_MODE == 1) {
          const int b = row / Lq;
          const int l = row - b * Lq;
          ((bf16*)Cptr)[((size_t)((b * NH + (col >> 6)) * Lq + l) << 6) + (col & 63)] =
              (bf16)val;
        } else {
          const int b = row >> 10;
          const int kv = row & 1023;
          ((bf16*)Cptr)[(((size_t)(b * NH + (col >> 6)) << 6) + (col & 63)) * 1024 + kv] =
              (bf16)val;
        }
      }
    }
  }
}

// ---------------------------------------------------------------------------
// Flash cross-attention, transposed formulation + register pipelining.
//   S^T = K Q^T ; O^T = V^T P^T. Per block: 128 q rows, 4 waves x 2 q-groups.
//   K tile double-buffered in registers (prefetch next while computing),
//   V loads issued at iteration start, consumed at PV (~400cy later).
// grid (4096/128, NH, B), 256 threads.
// ---------------------------------------------------------------------------
__global__ __launch_bounds__(256, 2) void attn_fused(const bf16* __restrict__ Q,
                                                     const bf16* __restrict__ K,
                                                     const bf16* __restrict__ VT,
                                                     bf16* __restrict__ O) {
  constexpr int LDP = 72;
  __shared__ bf16 Ptq[4][2][16 * LDP];

  const int qt = blockIdx.x;
  const int h = blockIdx.y;
  const int b = blockIdx.z;
  const int tid = threadIdx.x;
  const int w = tid >> 6;
  const int lane = tid & 63;
  const int quad = lane >> 4;
  const int l16 = lane & 15;

  const bf16* Qp = Q + ((size_t)(b * NH + h) * 4096 + qt * 128 + w * 32 + l16) * HD + quad * 8;
  const bf16* Kp = K + (size_t)(b * NH + h) * 1024 * HD + (size_t)l16 * HD + quad * 8;
  const bf16* Vp = VT + (size_t)(b * NH + h) * HD * 1024 + (size_t)l16 * 1024 + quad * 8;

  // Q B-fragments for the wave's two q-groups (rows w*32+g*16+l16)
  bf16x8 qf[2][2];
#pragma unroll
  for (int g = 0; g < 2; ++g)
#pragma unroll
    for (int s = 0; s < 2; ++s) qf[g][s] = *(const bf16x8*)(Qp + g * 16 * HD + s * 32);

  bf16* pw0 = &Ptq[w][0][l16 * LDP];
  bf16* pw1 = &Ptq[w][1][l16 * LDP];

  f32x4 oacc[2][4] = {};
  float lr0 = 0.f, lr1 = 0.f;

  bf16x8 kbufA[8], kbufB[8];

  auto kload = [&](bf16x8* dst, int kt) {
#pragma unroll
    for (int nt = 0; nt < 4; ++nt)
#pragma unroll
      for (int s = 0; s < 2; ++s)
        dst[nt * 2 + s] = *(const bf16x8*)(Kp + (size_t)(kt + nt * 16) * HD + s * 32);
  };

  kload(kbufA, 0);

  auto step = [&](int kt, bf16x8* kc, bf16x8* kn) {
    // V loads for THIS tile: issue now, consume at PV stage
    bf16x8 vv[8];
#pragma unroll
    for (int dt = 0; dt < 4; ++dt)
#pragma unroll
      for (int s = 0; s < 2; ++s)
        vv[dt * 2 + s] = *(const bf16x8*)(Vp + (size_t)(dt * 16) * 1024 + kt + s * 32);
    // K prefetch for NEXT tile (wraps harmlessly on the last iteration)
    kload(kn, (kt + 64) & 1023);

    // ---- S^T + softmax, both q-groups (kc shared)
#pragma unroll
    for (int g = 0; g < 2; ++g) {
      bf16* pw = g ? pw1 : pw0;
#pragma unroll
      for (int nt = 0; nt < 4; ++nt) {
        f32x4 a = {0.f, 0.f, 0.f, 0.f};
        a = MFMA16(kc[nt * 2 + 0], qf[g][0], a);
        a = MFMA16(kc[nt * 2 + 1], qf[g][1], a);
        bf16x4 pb;
        float ps = 0.f;
#pragma unroll
        for (int r = 0; r < 4; ++r) {
          const float p = __builtin_exp2f(fminf(a[r] * SCL2E, 80.f));
          ps += p;
          pb[r] = (bf16)p;
        }
        if (g) lr1 += ps; else lr0 += ps;
        *(bf16x4*)(pw + nt * 16 + quad * 4) = pb;
      }
    }

    // ---- P^T B-fragments (per-wave LDS, in-order r-after-w, no barrier)
    bf16x8 pf[2][2];
#pragma unroll
    for (int g = 0; g < 2; ++g) {
      const bf16* pw = g ? pw1 : pw0;
#pragma unroll
      for (int s = 0; s < 2; ++s)
        pf[g][s] = *(const bf16x8*)(pw + s * 32 + quad * 8);
    }

    // ---- O^T += V^T P^T
#pragma unroll
    for (int dt = 0; dt < 4; ++dt) {
      oacc[0][dt] = MFMA16(vv[dt * 2 + 0], pf[0][0], oacc[0][dt]);
      oacc[0][dt] = MFMA16(vv[dt * 2 + 1], pf[0][1], oacc[0][dt]);
      oacc[1][dt] = MFMA16(vv[dt * 2 + 0], pf[1][0], oacc[1][dt]);
      oacc[1][dt] = MFMA16(vv[dt * 2 + 1], pf[1][1], oacc[1][dt]);
    }
  };

  for (int kt = 0; kt < 1024; kt += 128) {
    step(kt, kbufA, kbufB);
    step(kt + 64, kbufB, kbufA);
  }

  // ---- finalize
  lr0 += __shfl_xor(lr0, 16);
  lr0 += __shfl_xor(lr0, 32);
  lr1 += __shfl_xor(lr1, 16);
  lr1 += __shfl_xor(lr1, 32);
  const float inv[2] = {1.f / lr0, 1.f / lr1};

#pragma unroll
  for (int g = 0; g < 2; ++g) {
    const size_t orow =
        ((size_t)(b * 4096 + qt * 128 + w * 32 + g * 16 + l16)) * DIM + h * 64;
#pragma unroll
    for (int dt = 0; dt < 4; ++dt) {
      bf16x4 ov = {(bf16)(oacc[g][dt][0] * inv[g]), (bf16)(oacc[g][dt][1] * inv[g]),
                   (bf16)(oacc[g][dt][2] * inv[g]), (bf16)(oacc[g][dt][3] * inv[g])};
      *(bf16x4*)(O + orow + dt * 16 + quad * 4) = ov;
    }
  }
}

// ---------------------------------------------------------------------------
extern "C" void kernel_launch(void* const* d_in, const int* in_sizes, int n_in,
                              void* d_out, int out_size, void* d_ws, size_t ws_size,
                              hipStream_t stream) {
  const float* x_broad = (const float*)d_in[0];
  const float* x_low = (const float*)d_in[1];
  const float* Wq = (const float*)d_in[2];
  const float* bq = (const float*)d_in[3];
  const float* Wk = (const float*)d_in[4];
  const float* bk = (const float*)d_in[5];
  const float* Wv = (const float*)d_in[6];
  const float* bv = (const float*)d_in[7];
  const float* Wo = (const float*)d_in[8];
  const float* bo = (const float*)d_in[9];

  constexpr int B = 4, L = 4096, LL = 1024;

  char* ws = (char*)d_ws;
  const size_t qBytes = (size_t)B * NH * L * HD * sizeof(bf16);
  const size_t kvBytes = (size_t)B * NH * LL * HD * sizeof(bf16);
  bf16* Qw = (bf16*)ws;
  bf16* Kw = (bf16*)(ws + qBytes);
  bf16* Vw = (bf16*)(ws + qBytes + kvBytes);
  bf16* Ow = (bf16*)(ws + qBytes + 2 * kvBytes);

  const dim3 blk(256);
  hipLaunchKernelGGL((gemm_nt<1, false>), dim3(B * L / 128, DIM / 128), blk, 0,
                     stream, x_broad, Wq, bq, Qw, L);
  hipLaunchKernelGGL((gemm_nt<1, false>), dim3(B * LL / 128, DIM / 128), blk, 0,
                     stream, x_low, Wk, bk, Kw, LL);
  hipLaunchKernelGGL((gemm_nt<2, false>), dim3(B * LL / 128, DIM / 128), blk, 0,
                     stream, x_low, Wv, bv, Vw, LL);
  hipLaunchKernelGGL(attn_fused, dim3(L / 128, NH, B), blk, 0, stream, Qw, Kw, Vw, Ow);
  hipLaunchKernelGGL((gemm_nt<0, true>), dim3(B * L / 128, DIM / 128), blk, 0,
                     stream, Ow, Wo, bo, d_out, 1);
}

// Round 4
// 407.646 us; speedup vs baseline: 1.9446x; 1.4276x over previous
//
#include <hip/hip_runtime.h>
#include <hip/hip_bf16.h>

typedef __bf16 bf16;
typedef __bf16 bf16x4 __attribute__((ext_vector_type(4)));
typedef __bf16 bf16x8 __attribute__((ext_vector_type(8)));
typedef float f32x4 __attribute__((ext_vector_type(4)));

#define MFMA16(a, b, c) __builtin_amdgcn_mfma_f32_16x16x32_bf16(a, b, c, 0, 0, 0)

constexpr int DIM = 1024;
constexpr int NH = 16;
constexpr int HD = 64;
constexpr float SCALE = 0.125f;
constexpr float L2E = 1.4426950408889634f;
constexpr float SCL2E = SCALE * L2E;

// async global->LDS, 16B per lane; lane i deposits at ldsbase + i*16
__device__ __forceinline__ void gl_lds16(const void* g, void* l) {
  __builtin_amdgcn_global_load_lds((const __attribute__((address_space(1))) void*)g,
                                   (__attribute__((address_space(3))) void*)l, 16, 0, 0);
}

// ---------------------------------------------------------------------------
// fp32 -> bf16 conversion (memory-bound, vectorized 8/thread)
// ---------------------------------------------------------------------------
__global__ __launch_bounds__(256) void cvt_f32_bf16(const float* __restrict__ s,
                                                    bf16* __restrict__ d, int n8) {
  const int i = blockIdx.x * 256 + threadIdx.x;
  if (i < n8) {
    const float4 v0 = ((const float4*)s)[i * 2];
    const float4 v1 = ((const float4*)s)[i * 2 + 1];
    bf16x8 o = {(bf16)v0.x, (bf16)v0.y, (bf16)v0.z, (bf16)v0.w,
                (bf16)v1.x, (bf16)v1.y, (bf16)v1.z, (bf16)v1.w};
    ((bf16x8*)d)[i] = o;
  }
}

// ---------------------------------------------------------------------------
// bf16 NT GEMM, m97 structure: global_load_lds staging + XOR swizzle.
// C[M,1024] = A[M,1024] @ W[1024,1024]^T + bias
// OUT_MODE 0: fp32 row-major; 1: bf16 head-major [B,NH,Lq,64]; 2: bf16 V^T.
// Swizzle: 16B chunk qc of tile-row r lives at LDS slot (r, qc ^ (r&7)).
// ---------------------------------------------------------------------------
template <int OUT_MODE>
__global__ __launch_bounds__(256) void gemm_bf16(const bf16* __restrict__ A,
                                                 const bf16* __restrict__ W,
                                                 const float* __restrict__ bias,
                                                 void* __restrict__ Cptr, int Lq) {
  __shared__ bf16 As[128 * 64];
  __shared__ bf16 Bs[128 * 64];

  const int bm = blockIdx.x * 128;
  const int bn = blockIdx.y * 128;
  const int tid = threadIdx.x;
  const int w = tid >> 6;
  const int lane = tid & 63;
  const int quad = lane >> 4;
  const int l16 = lane & 15;
  const int wm = (w >> 1) * 64;
  const int wn = (w & 1) * 64;
  const int lr = lane >> 3;                 // row offset within a stage call
  const int sc8 = (((lane & 7) ^ lr)) << 3; // swizzled source chunk (elems)
  const int x7 = l16 & 7;

  // per-lane global element offsets for the 4 stage rounds (A and B)
  size_t aOff[4], bOff[4];
#pragma unroll
  for (int r = 0; r < 4; ++r) {
    const int rowt = (r * 4 + w) * 8 + lr;
    aOff[r] = (size_t)(bm + rowt) * DIM + sc8;
    bOff[r] = (size_t)(bn + rowt) * DIM + sc8;
  }

  f32x4 acc[4][4] = {};

  for (int k0 = 0; k0 < DIM; k0 += 64) {
#pragma unroll
    for (int r = 0; r < 4; ++r) {
      gl_lds16(A + aOff[r] + k0, (char*)As + (r * 4 + w) * 1024);
      gl_lds16(W + bOff[r] + k0, (char*)Bs + (r * 4 + w) * 1024);
    }
    __syncthreads();  // vmcnt(0) drain -> tile resident

#pragma unroll
    for (int s = 0; s < 2; ++s) {
      bf16x8 af[4], bfr[4];
#pragma unroll
      for (int mi = 0; mi < 4; ++mi)
        af[mi] = *(const bf16x8*)((char*)As + (wm + mi * 16 + l16) * 128 +
                                  (((quad + 4 * s) ^ x7) << 4));
#pragma unroll
      for (int ni = 0; ni < 4; ++ni)
        bfr[ni] = *(const bf16x8*)((char*)Bs + (wn + ni * 16 + l16) * 128 +
                                   (((quad + 4 * s) ^ x7) << 4));
#pragma unroll
      for (int mi = 0; mi < 4; ++mi)
#pragma unroll
        for (int ni = 0; ni < 4; ++ni)
          acc[mi][ni] = MFMA16(af[mi], bfr[ni], acc[mi][ni]);
    }
    __syncthreads();  // reads done before next overwrite
  }

#pragma unroll
  for (int mi = 0; mi < 4; ++mi) {
#pragma unroll
    for (int ni = 0; ni < 4; ++ni) {
      const int col = bn + wn + ni * 16 + l16;
      const float bv = bias[col];
#pragma unroll
      for (int r = 0; r < 4; ++r) {
        const int row = bm + wm + mi * 16 + quad * 4 + r;
        const float val = acc[mi][ni][r] + bv;
        if constexpr (OUT_MODE == 0) {
          ((float*)Cptr)[(size_t)row * DIM + col] = val;
        } else if constexpr (OUT_MODE == 1) {
          const int b = row / Lq;
          const int l = row - b * Lq;
          ((bf16*)Cptr)[((size_t)((b * NH + (col >> 6)) * Lq + l) << 6) + (col & 63)] =
              (bf16)val;
        } else {
          const int b = row >> 10;
          const int kv = row & 1023;
          ((bf16*)Cptr)[(((size_t)(b * NH + (col >> 6)) << 6) + (col & 63)) * 1024 + kv] =
              (bf16)val;
        }
      }
    }
  }
}

// ---------------------------------------------------------------------------
// Legacy fp32-input GEMM (R3) — fallback when ws is too small for bf16 path.
// ---------------------------------------------------------------------------
template <int OUT_MODE, bool A_BF16>
__global__ __launch_bounds__(256) void gemm_nt(const void* __restrict__ Aptr,
                                               const float* __restrict__ W,
                                               const float* __restrict__ bias,
                                               void* __restrict__ Cptr, int Lq) {
  constexpr int LDT = 72;
  __shared__ bf16 As[128 * LDT];
  __shared__ bf16 Bs[128 * LDT];

  const int bm = blockIdx.x * 128;
  const int bn = blockIdx.y * 128;
  const int tid = threadIdx.x;
  const int w = tid >> 6;
  const int lane = tid & 63;
  const int quad = lane >> 4;
  const int l16 = lane & 15;
  const int wm = (w >> 1) * 64;
  const int wn = (w & 1) * 64;

  f32x4 acc[4][4] = {};

  for (int k0 = 0; k0 < DIM; k0 += 64) {
#pragma unroll
    for (int i = 0; i < 8; ++i) {
      int f = i * 256 + tid;
      int row = f >> 4;
      int c4 = (f & 15) << 2;
      const float4 v = *(const float4*)(W + (size_t)(bn + row) * DIM + k0 + c4);
      bf16x4 bv = {(bf16)v.x, (bf16)v.y, (bf16)v.z, (bf16)v.w};
      *(bf16x4*)&Bs[row * LDT + c4] = bv;
    }
    if constexpr (A_BF16) {
      const bf16* Ab = (const bf16*)Aptr;
#pragma unroll
      for (int i = 0; i < 4; ++i) {
        int f = i * 256 + tid;
        int row = f >> 3;
        int c8 = (f & 7) << 3;
        *(bf16x8*)&As[row * LDT + c8] =
            *(const bf16x8*)(Ab + (size_t)(bm + row) * DIM + k0 + c8);
      }
    } else {
      const float* Af = (const float*)Aptr;
#pragma unroll
      for (int i = 0; i < 8; ++i) {
        int f = i * 256 + tid;
        int row = f >> 4;
        int c4 = (f & 15) << 2;
        const float4 v = *(const float4*)(Af + (size_t)(bm + row) * DIM + k0 + c4);
        bf16x4 av = {(bf16)v.x, (bf16)v.y, (bf16)v.z, (bf16)v.w};
        *(bf16x4*)&As[row * LDT + c4] = av;
      }
    }
    __syncthreads();

#pragma unroll
    for (int sub = 0; sub < 2; ++sub) {
      bf16x8 af[4], bfr[4];
#pragma unroll
      for (int mi = 0; mi < 4; ++mi)
        af[mi] = *(const bf16x8*)&As[(wm + mi * 16 + l16) * LDT + sub * 32 + quad * 8];
#pragma unroll
      for (int ni = 0; ni < 4; ++ni)
        bfr[ni] = *(const bf16x8*)&Bs[(wn + ni * 16 + l16) * LDT + sub * 32 + quad * 8];
#pragma unroll
      for (int mi = 0; mi < 4; ++mi)
#pragma unroll
        for (int ni = 0; ni < 4; ++ni)
          acc[mi][ni] = MFMA16(af[mi], bfr[ni], acc[mi][ni]);
    }
    __syncthreads();
  }

#pragma unroll
  for (int mi = 0; mi < 4; ++mi) {
#pragma unroll
    for (int ni = 0; ni < 4; ++ni) {
      const int col = bn + wn + ni * 16 + l16;
      const float bv = bias[col];
#pragma unroll
      for (int r = 0; r < 4; ++r) {
        const int row = bm + wm + mi * 16 + quad * 4 + r;
        const float val = acc[mi][ni][r] + bv;
        if constexpr (OUT_MODE == 0) {
          ((float*)Cptr)[(size_t)row * DIM + col] = val;
        } else if constexpr (OUT_MODE == 1) {
          const int b = row / Lq;
          const int l = row - b * Lq;
          ((bf16*)Cptr)[((size_t)((b * NH + (col >> 6)) * Lq + l) << 6) + (col & 63)] =
              (bf16)val;
        } else {
          const int b = row >> 10;
          const int kv = row & 1023;
          ((bf16*)Cptr)[(((size_t)(b * NH + (col >> 6)) << 6) + (col & 63)) * 1024 + kv] =
              (bf16)val;
        }
      }
    }
  }
}

// ---------------------------------------------------------------------------
// Flash cross-attention, transposed formulation, LDS-staged K/V.
//   S^T = K Q^T ; O^T = V^T P^T. 128 q rows/block, 4 waves x 2 q-groups.
//   K,V^T 64x64 tiles double-buffered in LDS via swizzled global_load_lds;
//   one barrier per step (stage k+1 right after draining tile k).
// grid (4096/128, NH, B), 256 threads.
// ---------------------------------------------------------------------------
__global__ __launch_bounds__(256) void attn_fused(const bf16* __restrict__ Q,
                                                  const bf16* __restrict__ K,
                                                  const bf16* __restrict__ VT,
                                                  bf16* __restrict__ O) {
  constexpr int LDP = 72;
  __shared__ bf16 Ks[2][64 * 64];
  __shared__ bf16 Vs[2][64 * 64];
  __shared__ bf16 Ps[4 * 2 * 16 * LDP];

  const int qt = blockIdx.x;
  const int h = blockIdx.y;
  const int b = blockIdx.z;
  const int tid = threadIdx.x;
  const int w = tid >> 6;
  const int lane = tid & 63;
  const int quad = lane >> 4;
  const int l16 = lane & 15;
  const int lr = lane >> 3;
  const int sc8 = (((lane & 7) ^ lr)) << 3;
  const int x7 = l16 & 7;

  const bf16* Qp = Q + ((size_t)(b * NH + h) * 4096 + qt * 128 + w * 32 + l16) * HD + quad * 8;
  const bf16* Kb = K + (size_t)(b * NH + h) * 1024 * HD;
  const bf16* Vb = VT + (size_t)(b * NH + h) * HD * 1024;

  bf16x8 qf[2][2];
#pragma unroll
  for (int g = 0; g < 2; ++g)
#pragma unroll
    for (int s = 0; s < 2; ++s) qf[g][s] = *(const bf16x8*)(Qp + g * 16 * HD + s * 32);

  bf16* pw0 = &Ps[(w * 2 + 0) * 16 * LDP];
  bf16* pw1 = &Ps[(w * 2 + 1) * 16 * LDP];

  f32x4 oacc[2][4] = {};
  float lq0 = 0.f, lq1 = 0.f;

  auto stage = [&](int kt, int bi) {
#pragma unroll
    for (int c2 = 0; c2 < 2; ++c2) {
      const int c = c2 * 4 + w;
      gl_lds16(Kb + (size_t)(kt + c * 8 + lr) * HD + sc8, (char*)&Ks[bi][0] + c * 1024);
      gl_lds16(Vb + (size_t)(c * 8 + lr) * 1024 + kt + sc8, (char*)&Vs[bi][0] + c * 1024);
    }
  };

  stage(0, 0);
  int buf = 0;
  for (int kt = 0; kt < 1024; kt += 64) {
    __syncthreads();  // drains this tile's global_load_lds (vmcnt0) + syncs waves
    if (kt + 64 < 1024) stage(kt + 64, buf ^ 1);

    // ---- K fragments (shared by both q-groups), swizzled LDS reads
    bf16x8 kf[4][2];
#pragma unroll
    for (int nt = 0; nt < 4; ++nt)
#pragma unroll
      for (int s = 0; s < 2; ++s)
        kf[nt][s] = *(const bf16x8*)((char*)&Ks[buf][0] + (nt * 16 + l16) * 128 +
                                     (((quad + 4 * s) ^ x7) << 4));

    // ---- S^T + exp + P store
#pragma unroll
    for (int g = 0; g < 2; ++g) {
      bf16* pw = g ? pw1 : pw0;
      float lsum = 0.f;
#pragma unroll
      for (int nt = 0; nt < 4; ++nt) {
        f32x4 a = {0.f, 0.f, 0.f, 0.f};
        a = MFMA16(kf[nt][0], qf[g][0], a);
        a = MFMA16(kf[nt][1], qf[g][1], a);
        bf16x4 pb;
#pragma unroll
        for (int r = 0; r < 4; ++r) {
          const float p = __builtin_exp2f(a[r] * SCL2E);
          lsum += p;
          pb[r] = (bf16)p;
        }
        *(bf16x4*)(pw + l16 * LDP + nt * 16 + quad * 4) = pb;
      }
      if (g) lq1 += lsum; else lq0 += lsum;
    }

    // ---- P^T B-fragments (per-wave LDS, in-order, no barrier)
    bf16x8 pf[2][2];
#pragma unroll
    for (int g = 0; g < 2; ++g) {
      const bf16* pw = g ? pw1 : pw0;
#pragma unroll
      for (int s = 0; s < 2; ++s)
        pf[g][s] = *(const bf16x8*)(pw + l16 * LDP + s * 32 + quad * 8);
    }

    // ---- V^T fragments + O^T += V^T P^T
#pragma unroll
    for (int dt = 0; dt < 4; ++dt) {
      bf16x8 vf0 = *(const bf16x8*)((char*)&Vs[buf][0] + (dt * 16 + l16) * 128 +
                                    ((quad ^ x7) << 4));
      bf16x8 vf1 = *(const bf16x8*)((char*)&Vs[buf][0] + (dt * 16 + l16) * 128 +
                                    ((((quad + 4)) ^ x7) << 4));
      oacc[0][dt] = MFMA16(vf0, pf[0][0], oacc[0][dt]);
      oacc[0][dt] = MFMA16(vf1, pf[0][1], oacc[0][dt]);
      oacc[1][dt] = MFMA16(vf0, pf[1][0], oacc[1][dt]);
      oacc[1][dt] = MFMA16(vf1, pf[1][1], oacc[1][dt]);
    }
    buf ^= 1;
  }

  // ---- finalize
  lq0 += __shfl_xor(lq0, 16);
  lq0 += __shfl_xor(lq0, 32);
  lq1 += __shfl_xor(lq1, 16);
  lq1 += __shfl_xor(lq1, 32);
  const float inv[2] = {1.f / lq0, 1.f / lq1};

#pragma unroll
  for (int g = 0; g < 2; ++g) {
    const size_t orow =
        ((size_t)(b * 4096 + qt * 128 + w * 32 + g * 16 + l16)) * DIM + h * 64;
#pragma unroll
    for (int dt = 0; dt < 4; ++dt) {
      bf16x4 ov = {(bf16)(oacc[g][dt][0] * inv[g]), (bf16)(oacc[g][dt][1] * inv[g]),
                   (bf16)(oacc[g][dt][2] * inv[g]), (bf16)(oacc[g][dt][3] * inv[g])};
      *(bf16x4*)(O + orow + dt * 16 + quad * 4) = ov;
    }
  }
}

// ---------------------------------------------------------------------------
extern "C" void kernel_launch(void* const* d_in, const int* in_sizes, int n_in,
                              void* d_out, int out_size, void* d_ws, size_t ws_size,
                              hipStream_t stream) {
  const float* x_broad = (const float*)d_in[0];
  const float* x_low = (const float*)d_in[1];
  const float* Wq = (const float*)d_in[2];
  const float* bq = (const float*)d_in[3];
  const float* Wk = (const float*)d_in[4];
  const float* bk = (const float*)d_in[5];
  const float* Wv = (const float*)d_in[6];
  const float* bv = (const float*)d_in[7];
  const float* Wo = (const float*)d_in[8];
  const float* bo = (const float*)d_in[9];

  constexpr int B = 4, L = 4096, LL = 1024;
  const size_t qBytes = (size_t)B * NH * L * HD * 2;    // 33.55 MB
  const size_t kvBytes = (size_t)B * NH * LL * HD * 2;  //  8.39 MB
  const size_t oBytes = qBytes;                          // 33.55 MB (O / xb_bf alias)
  const size_t xlBytes = kvBytes;                        //  8.39 MB
  const size_t wBytes = (size_t)DIM * DIM * 2;           //  2.10 MB each

  char* ws = (char*)d_ws;
  bf16* Qw = (bf16*)ws;
  bf16* Kw = (bf16*)(ws + qBytes);
  bf16* Vw = (bf16*)(ws + qBytes + kvBytes);
  bf16* Ow = (bf16*)(ws + qBytes + 2 * kvBytes);

  const dim3 blk(256);
  const size_t need = qBytes + 2 * kvBytes + oBytes + xlBytes + 4 * wBytes;

  if (ws_size >= need) {
    // bf16 fast path: Ow region doubles as xb_bf (consumed by Q-proj before attn writes O)
    bf16* xbB = Ow;
    bf16* xlB = (bf16*)(ws + qBytes + 2 * kvBytes + oBytes);
    bf16* WqB = (bf16*)(ws + qBytes + 2 * kvBytes + oBytes + xlBytes);
    bf16* WkB = WqB + (size_t)DIM * DIM;
    bf16* WvB = WkB + (size_t)DIM * DIM;
    bf16* WoB = WvB + (size_t)DIM * DIM;

    hipLaunchKernelGGL(cvt_f32_bf16, dim3(B * L * DIM / 8 / 256), blk, 0, stream,
                       x_broad, xbB, B * L * DIM / 8);
    hipLaunchKernelGGL(cvt_f32_bf16, dim3(B * LL * DIM / 8 / 256), blk, 0, stream,
                       x_low, xlB, B * LL * DIM / 8);
    hipLaunchKernelGGL(cvt_f32_bf16, dim3(DIM * DIM / 8 / 256), blk, 0, stream, Wq, WqB,
                       DIM * DIM / 8);
    hipLaunchKernelGGL(cvt_f32_bf16, dim3(DIM * DIM / 8 / 256), blk, 0, stream, Wk, WkB,
                       DIM * DIM / 8);
    hipLaunchKernelGGL(cvt_f32_bf16, dim3(DIM * DIM / 8 / 256), blk, 0, stream, Wv, WvB,
                       DIM * DIM / 8);
    hipLaunchKernelGGL(cvt_f32_bf16, dim3(DIM * DIM / 8 / 256), blk, 0, stream, Wo, WoB,
                       DIM * DIM / 8);

    hipLaunchKernelGGL((gemm_bf16<1>), dim3(B * L / 128, DIM / 128), blk, 0, stream,
                       xbB, WqB, bq, Qw, L);
    hipLaunchKernelGGL((gemm_bf16<1>), dim3(B * LL / 128, DIM / 128), blk, 0, stream,
                       xlB, WkB, bk, Kw, LL);
    hipLaunchKernelGGL((gemm_bf16<2>), dim3(B * LL / 128, DIM / 128), blk, 0, stream,
                       xlB, WvB, bv, Vw, LL);
    hipLaunchKernelGGL(attn_fused, dim3(L / 128, NH, B), blk, 0, stream, Qw, Kw, Vw, Ow);
    hipLaunchKernelGGL((gemm_bf16<0>), dim3(B * L / 128, DIM / 128), blk, 0, stream,
                       Ow, WoB, bo, d_out, 1);
  } else {
    // fallback: fp32-input GEMMs (R3), same attention
    hipLaunchKernelGGL((gemm_nt<1, false>), dim3(B * L / 128, DIM / 128), blk, 0,
                       stream, x_broad, Wq, bq, Qw, L);
    hipLaunchKernelGGL((gemm_nt<1, false>), dim3(B * LL / 128, DIM / 128), blk, 0,
                       stream, x_low, Wk, bk, Kw, LL);
    hipLaunchKernelGGL((gemm_nt<2, false>), dim3(B * LL / 128, DIM / 128), blk, 0,
                       stream, x_low, Wv, bv, Vw, LL);
    hipLaunchKernelGGL(attn_fused, dim3(L / 128, NH, B), blk, 0, stream, Qw, Kw, Vw, Ow);
    hipLaunchKernelGGL((gemm_nt<0, true>), dim3(B * L / 128, DIM / 128), blk, 0,
                       stream, Ow, Wo, bo, d_out, 1);
  }
}